// Round 17
// baseline (102.423 us; speedup 1.0000x reference)
//
#include <hip/hip_runtime.h>
#include <hip/hip_bf16.h>
#include <math.h>

#define NSUP 50000
#define NQ   50000
#define NH   32
#define NK   15
#define NG   8
#define INV_SIGMA (1.0f/0.6f)
#define GN_EPS 1e-5f
#define NEG  0.1f

#define QB   16
#define NBLK (NQ/QB)       // 3125

// workspace layout (float offsets) — R9-proven sizes
#define OFF_ROWSUM 0
#define OFF_FB     50048                        // ushort[50000*64] = 1.6M float slots
#define OFF_WB     (OFF_FB + 1600000)           // ushort[61440] fragment-packed W
#define OFF_PS     (OFF_WB + 30720)
#define OFF_PQ     (OFF_PS + NBLK*8)

typedef __attribute__((ext_vector_type(8))) short bf16x8;
typedef __attribute__((ext_vector_type(4))) float f32x4;
typedef __attribute__((ext_vector_type(4))) unsigned int u32x4;

__device__ __forceinline__ short f2bf(float x) {
    __hip_bfloat16 h = __float2bfloat16(x);
    return *reinterpret_cast<short*>(&h);
}

// ---------------- kernel 0: rowsum + fb convert (blocks < 3125), wpack (rest)
__global__ __launch_bounds__(256) void k_prep(const float* __restrict__ sf,
                                              float* __restrict__ rowsum,
                                              unsigned short* __restrict__ fb,
                                              const float* __restrict__ wts,
                                              unsigned short* __restrict__ wb) {
    if (blockIdx.x < 3125) {
        // 16 rows/block; each 16-lane group = one row as 16 x float4
        const int lane = threadIdx.x & 63;
        const int row  = blockIdx.x * 16 + (threadIdx.x >> 6) * 4 + (lane >> 4);
        const int c4   = lane & 15;
        const float4 v = ((const float4*)sf)[(size_t)row * 16 + c4];
        ushort4 b;
        b.x = (unsigned short)f2bf(v.x); b.y = (unsigned short)f2bf(v.y);
        b.z = (unsigned short)f2bf(v.z); b.w = (unsigned short)f2bf(v.w);
        *(ushort4*)&fb[(size_t)row * 64 + c4 * 4] = b;
        float s = v.x + v.y + v.z + v.w;
        #pragma unroll
        for (int o = 1; o <= 8; o <<= 1) s += __shfl_xor(s, o);
        if (c4 == 0) rowsum[row] = s;
    } else {
        // pack W into B-fragment order (R2-exact):
        // [ks(30)][n(4)][lane(64)][j(8)] ; value = W[ks*32+(l>>4)*8+j][n*16+(l&15)]
        int idx = (blockIdx.x - 3125) * 256 + threadIdx.x;
        if (idx >= 30 * 4 * 64 * 8) return;
        int j  = idx & 7;
        int l  = (idx >> 3) & 63;
        int n  = (idx >> 9) & 3;
        int ks = idx >> 11;
        int r  = ks * 32 + ((l >> 4) << 3) + j;
        int d  = n * 16 + (l & 15);
        wb[idx] = (unsigned short)f2bf(wts[(size_t)r * 64 + d]);
    }
}

// ---------------- kernel 1: fused KPConv, 2 q-tiles per block -----------------
__global__ __launch_bounds__(256, 5) void k_conv(
    const unsigned short* __restrict__ fb, const float* __restrict__ qpts,
    const float* __restrict__ spts,  const int*   __restrict__ nidx,
    const float* __restrict__ kpts,  const unsigned short* __restrict__ wb,
    const float* __restrict__ bias,  const float* __restrict__ rowsum,
    float* __restrict__ conv_out, float* __restrict__ part_s, float* __restrict__ part_q)
{
    __shared__ __align__(16) short wl16[16 * 968];
    __shared__ __align__(16) float kp4[16][4];
    __shared__ float rcl[16];

    const int tid  = threadIdx.x;
    const int wv   = tid >> 6;
    const int lane = tid & 63;
    const int g    = lane >> 4;
    const int c16  = lane & 15;

    if (tid < 16) {
        if (tid < NK) {
            kp4[tid][0] = kpts[tid*3+0];
            kp4[tid][1] = kpts[tid*3+1];
            kp4[tid][2] = kpts[tid*3+2];
        } else {
            kp4[tid][0] = 1e8f; kp4[tid][1] = 1e8f; kp4[tid][2] = 1e8f;  // k=15 -> w=0
        }
        kp4[tid][3] = 0.f;
    }
    __syncthreads();

    const float kx = kp4[c16][0], ky = kp4[c16][1], kz = kp4[c16][2];

    char*  WV  = (char*)wl16 + wv * 7424;
    float* XYP = (float*)WV;               // [(pp*64 + half*32 + h)*5 + comp]
    char*  FP  = WV + 2560;                // [32 h][144B], chunk XOR

    const int h    = lane & 31;
    const int half = lane >> 5;
    const int gr   = lane >> 3;   // row slot 0..7
    const int gs   = lane & 7;    // 16B chunk 0..7

    #pragma unroll 1
    for (int t = 0; t < 2; t++) {
        const int tile = blockIdx.x * 2 + t;
        if (tile >= NBLK) break;
        const int qbase = tile * QB;

        f32x4 pacc[4][4];
        #pragma unroll
        for (int a = 0; a < 4; a++)
            #pragma unroll
            for (int b = 0; b < 4; b++) pacc[a][b] = (f32x4){0.f,0.f,0.f,0.f};

        // ---- phase-0: dxyz staging + valid-count ----------------------------
        #pragma unroll
        for (int pp = 0; pp < 2; pp++) {
            const int qq = pp*2 + half;
            const int m  = qbase + wv*4 + qq;
            const float qx = qpts[m*3+0], qy = qpts[m*3+1], qz = qpts[m*3+2];
            const int  id  = nidx[(size_t)m * NH + h];
            const bool val = (id < NSUP);
            const int  ii  = val ? id : 0;
            const float dx = spts[ii*3+0]-qx, dy = spts[ii*3+1]-qy, dz = spts[ii*3+2]-qz;
            const float rs = rowsum[ii];
            unsigned long long bal = __ballot(val && rs > 0.f);
            int cA = __popcll(bal & 0xffffffffull); if (cA < 1) cA = 1;
            int cB = __popcll(bal >> 32);           if (cB < 1) cB = 1;
            if (lane == 0)  rcl[wv*4 + pp*2]     = 1.0f / (float)cA;
            if (lane == 32) rcl[wv*4 + pp*2 + 1] = 1.0f / (float)cB;
            const int si = (pp*64 + half*32 + h) * 5;
            XYP[si]     = val ? dx : 1e10f;
            XYP[si + 1] = dy;
            XYP[si + 2] = dz;
        }

        // ---- gather pipeline (depth-1, R9-proven) ---------------------------
        int   idA[4], idB[4];
        u32x4 vA[4], vB[4];
        {
            const int m0 = qbase + wv*4;
            #pragma unroll
            for (int i = 0; i < 4; i++) idA[i] = nidx[(size_t)m0*NH + i*8 + gr];
            #pragma unroll
            for (int i = 0; i < 4; i++) {
                const int id2 = (idA[i] < NSUP) ? idA[i] : 0;
                vA[i] = *(const u32x4*)((const char*)fb + (size_t)id2*128 + gs*16);
            }
            const int m1 = qbase + wv*4 + 1;
            #pragma unroll
            for (int i = 0; i < 4; i++) idB[i] = nidx[(size_t)m1*NH + i*8 + gr];
        }

        #pragma unroll
        for (int q = 0; q < 4; q++) {      // fully unrolled: all indices constant
            const int pp = q >> 1, e = q & 1;
            u32x4* vc  = (q & 1) ? vB  : vA;
            u32x4* vn  = (q & 1) ? vA  : vB;
            int*   idn = (q & 1) ? idA : idB;
            int*   idt = (q & 1) ? idB : idA;

            #pragma unroll
            for (int i = 0; i < 4; i++)
                *(u32x4*)(FP + (i*8 + gr)*144 + ((gs ^ i) << 4)) = vc[i];

            if (q < 3) {
                #pragma unroll
                for (int i = 0; i < 4; i++) {
                    const int id2 = (idn[i] < NSUP) ? idn[i] : 0;
                    vn[i] = *(const u32x4*)((const char*)fb + (size_t)id2*128 + gs*16);
                }
            }
            if (q < 2) {
                const int mn = qbase + wv*4 + q + 2;
                #pragma unroll
                for (int i = 0; i < 4; i++) idt[i] = nidx[(size_t)mn*NH + i*8 + gr];
            }

            union { unsigned short u[8]; bf16x8 v; } ua;
            #pragma unroll
            for (int j = 0; j < 8; j++) {
                const int xi = (pp*64 + e*32 + g*8 + j) * 5;
                const float px = XYP[xi], py = XYP[xi+1], pz = XYP[xi+2];
                const float ex = px - kx, ey = py - ky, ez = pz - kz;
                const float sq = fmaf(ex, ex, fmaf(ey, ey, ez * ez));
                const float w  = fmaxf(1.0f - sqrtf(sq) * INV_SIGMA, 0.f);
                ua.u[j] = (unsigned short)f2bf(w);
            }

            #pragma unroll
            for (int ct = 0; ct < 4; ct++) {
                const char* vb = FP + (g*8)*144
                               + (((((ct << 1) | (c16 >> 3)) ^ g) & 7) << 4)
                               + ((c16 & 7) << 1);
                union { unsigned short u[8]; bf16x8 v; } ub;
                #pragma unroll
                for (int j = 0; j < 8; j++)
                    ub.u[j] = *(const unsigned short*)(vb + j*144);
                pacc[q][ct] = __builtin_amdgcn_mfma_f32_16x16x32_bf16(ua.v, ub.v, pacc[q][ct], 0, 0, 0);
            }
        }

        __syncthreads();     // phase-1 LDS dead; wl16 becomes the phase-2 A matrix

        #pragma unroll
        for (int qq = 0; qq < 4; qq++) {
            #pragma unroll
            for (int ct = 0; ct < 4; ct++) {
                #pragma unroll
                for (int i = 0; i < 4; i++) {
                    const int kk = g*4 + i;
                    if (kk < NK)
                        wl16[(wv*4 + qq)*968 + kk*64 + ct*16 + c16] = f2bf(pacc[qq][ct][i]);
                }
            }
        }
        __syncthreads();

        f32x4 facc = (f32x4){0.f,0.f,0.f,0.f};
        const int z = lane >> 4;
        const short* ap = wl16 + c16*968 + z*8;
        const unsigned short* bp = wb + ((size_t)(wv * 64 + lane)) * 8;
        #pragma unroll 6
        for (int ks = 0; ks < 30; ks++) {
            bf16x8 a = *(const bf16x8*)(ap + ks*32);
            bf16x8 b = *(const bf16x8*)(bp + (size_t)ks*2048);
            facc = __builtin_amdgcn_mfma_f32_16x16x32_bf16(a, b, facc, 0, 0, 0);
        }

        const int   d  = wv*16 + c16;
        const float bs = bias[d];
        float gl = 0.f, gq = 0.f;
        #pragma unroll
        for (int i = 0; i < 4; i++) {
            const int row = z*4 + i;
            const float y = facc[i] * rcl[row] + bs;
            conv_out[(size_t)(qbase + row)*64 + d] = y;
            gl += y;
            gq = fmaf(y, y, gq);
        }
        #pragma unroll
        for (int msk = 1; msk <= 4; msk <<= 1) { gl += __shfl_xor(gl, msk); gq += __shfl_xor(gq, msk); }
        gl += __shfl_xor(gl, 16); gq += __shfl_xor(gq, 16);
        gl += __shfl_xor(gl, 32); gq += __shfl_xor(gq, 32);
        if ((lane & 55) == 0) {
            const int grp = wv*2 + (lane >> 3);
            part_s[(size_t)tile * 8 + grp] = gl;
            part_q[(size_t)tile * 8 + grp] = gq;
        }

        __syncthreads();   // protect rcl + wl16 overlay before next tile's phase-0
    }
}

// ---------------- kernel 2: fused deterministic stats + GN + LeakyReLU --------
__global__ __launch_bounds__(256) void k_apply(float* __restrict__ out,
                                               const float* __restrict__ part_s,
                                               const float* __restrict__ part_q,
                                               const float* __restrict__ gamma,
                                               const float* __restrict__ beta) {
    __shared__ double ds[32][8], dq[32][8];
    __shared__ float st[16];
    const int t = threadIdx.x;

    // every block computes the SAME reduction in the SAME order -> identical stats
    {
        const int gg = t & 7, chunk = t >> 3;
        const int per = (NBLK + 31) / 32;          // 98
        int lo = chunk * per, hi = lo + per; if (hi > NBLK) hi = NBLK;
        double s0 = 0.0, s1 = 0.0, s2 = 0.0, s3 = 0.0;
        double q0 = 0.0, q1 = 0.0, q2 = 0.0, q3 = 0.0;
        int i = lo;
        for (; i + 3 < hi; i += 4) {
            s0 += (double)part_s[(size_t)(i+0) * 8 + gg];
            s1 += (double)part_s[(size_t)(i+1) * 8 + gg];
            s2 += (double)part_s[(size_t)(i+2) * 8 + gg];
            s3 += (double)part_s[(size_t)(i+3) * 8 + gg];
            q0 += (double)part_q[(size_t)(i+0) * 8 + gg];
            q1 += (double)part_q[(size_t)(i+1) * 8 + gg];
            q2 += (double)part_q[(size_t)(i+2) * 8 + gg];
            q3 += (double)part_q[(size_t)(i+3) * 8 + gg];
        }
        for (; i < hi; i++) {
            s0 += (double)part_s[(size_t)i * 8 + gg];
            q0 += (double)part_q[(size_t)i * 8 + gg];
        }
        ds[chunk][gg] = (s0 + s1) + (s2 + s3);
        dq[chunk][gg] = (q0 + q1) + (q2 + q3);
        __syncthreads();
        if (t < 8) {
            double S = 0.0, Q = 0.0;
            for (int cix = 0; cix < 32; cix++) { S += ds[cix][t]; Q += dq[cix][t]; }
            const double cnt = (double)(64 / NG) * (double)NQ;   // 400000
            double mean = S / cnt;
            double var  = Q / cnt - mean * mean;
            st[t]     = (float)mean;
            st[8 + t] = (float)(1.0 / sqrt(var + (double)GN_EPS));
        }
        __syncthreads();
    }

    // normalize + affine + LeakyReLU, in place on d_out (same thread R+W)
    const int n4 = NQ * 64 / 4;
    for (int idx = blockIdx.x * 256 + t; idx < n4; idx += gridDim.x * 256) {
        float4 v = ((const float4*)out)[idx];
        const int c4 = idx & 15;
        const int g  = c4 >> 1;
        const float mean = st[g], istd = st[8 + g];
        const float4 ga = ((const float4*)gamma)[c4];
        const float4 be = ((const float4*)beta)[c4];
        float4 r;
        r.x = (v.x - mean) * istd * ga.x + be.x; r.x = r.x >= 0.f ? r.x : NEG * r.x;
        r.y = (v.y - mean) * istd * ga.y + be.y; r.y = r.y >= 0.f ? r.y : NEG * r.y;
        r.z = (v.z - mean) * istd * ga.z + be.z; r.z = r.z >= 0.f ? r.z : NEG * r.z;
        r.w = (v.w - mean) * istd * ga.w + be.w; r.w = r.w >= 0.f ? r.w : NEG * r.w;
        ((float4*)out)[idx] = r;
    }
}

extern "C" void kernel_launch(void* const* d_in, const int* in_sizes, int n_in,
                              void* d_out, int out_size, void* d_ws, size_t ws_size,
                              hipStream_t stream) {
    const float* sfeats = (const float*)d_in[0];
    const float* qpts   = (const float*)d_in[1];
    const float* spts   = (const float*)d_in[2];
    const int*   nidx   = (const int*)  d_in[3];
    const float* kpts   = (const float*)d_in[4];
    const float* wts    = (const float*)d_in[5];
    const float* bias   = (const float*)d_in[6];
    const float* gamma  = (const float*)d_in[7];
    const float* beta   = (const float*)d_in[8];

    float* ws = (float*)d_ws;
    float*          rowsum = ws + OFF_ROWSUM;
    unsigned short* fb     = (unsigned short*)(ws + OFF_FB);
    unsigned short* wb     = (unsigned short*)(ws + OFF_WB);
    float*          ps     = ws + OFF_PS;
    float*          pq     = ws + OFF_PQ;
    float*          out    = (float*)d_out;

    k_prep <<<dim3(3365), dim3(256), 0, stream>>>(sfeats, rowsum, fb, wts, wb);
    k_conv <<<dim3((NBLK + 1) / 2), dim3(256), 0, stream>>>(fb, qpts, spts, nidx, kpts,
                                                            wb, bias, rowsum, out, ps, pq);
    k_apply<<<dim3(512), dim3(256), 0, stream>>>(out, ps, pq, gamma, beta);
}

// Round 18
// 74.459 us; speedup vs baseline: 1.3756x; 1.3756x over previous
//
#include <hip/hip_runtime.h>
#include <hip/hip_bf16.h>
#include <math.h>

#define NSUP 50000
#define NQ   50000
#define NH   32
#define NK   15
#define NG   8
#define INV_SIGMA (1.0f/0.6f)
#define GN_EPS 1e-5f
#define NEG  0.1f

#define QB   16
#define NBLK (NQ/QB)       // 3125

// workspace layout (float offsets) — R9-proven sizes
#define OFF_ROWSUM 0
#define OFF_FB     50048                        // ushort[50000*64] = 1.6M float slots
#define OFF_WB     (OFF_FB + 1600000)           // ushort[61440] fragment-packed W
#define OFF_PS     (OFF_WB + 30720)
#define OFF_PQ     (OFF_PS + NBLK*8)

typedef __attribute__((ext_vector_type(8))) short bf16x8;
typedef __attribute__((ext_vector_type(4))) float f32x4;
typedef __attribute__((ext_vector_type(4))) unsigned int u32x4;

__device__ __forceinline__ short f2bf(float x) {
    __hip_bfloat16 h = __float2bfloat16(x);
    return *reinterpret_cast<short*>(&h);
}

// ---------------- kernel 0: rowsum + fb convert (blocks < 3125), wpack (rest)
__global__ __launch_bounds__(256) void k_prep(const float* __restrict__ sf,
                                              float* __restrict__ rowsum,
                                              unsigned short* __restrict__ fb,
                                              const float* __restrict__ wts,
                                              unsigned short* __restrict__ wb) {
    if (blockIdx.x < 3125) {
        // 16 rows/block; each 16-lane group = one row as 16 x float4
        const int lane = threadIdx.x & 63;
        const int row  = blockIdx.x * 16 + (threadIdx.x >> 6) * 4 + (lane >> 4);
        const int c4   = lane & 15;
        const float4 v = ((const float4*)sf)[(size_t)row * 16 + c4];
        ushort4 b;
        b.x = (unsigned short)f2bf(v.x); b.y = (unsigned short)f2bf(v.y);
        b.z = (unsigned short)f2bf(v.z); b.w = (unsigned short)f2bf(v.w);
        *(ushort4*)&fb[(size_t)row * 64 + c4 * 4] = b;
        float s = v.x + v.y + v.z + v.w;
        #pragma unroll
        for (int o = 1; o <= 8; o <<= 1) s += __shfl_xor(s, o);
        if (c4 == 0) rowsum[row] = s;
    } else {
        // pack W into B-fragment order (R2-exact):
        // [ks(30)][n(4)][lane(64)][j(8)] ; value = W[ks*32+(l>>4)*8+j][n*16+(l&15)]
        int idx = (blockIdx.x - 3125) * 256 + threadIdx.x;
        if (idx >= 30 * 4 * 64 * 8) return;
        int j  = idx & 7;
        int l  = (idx >> 3) & 63;
        int n  = (idx >> 9) & 3;
        int ks = idx >> 11;
        int r  = ks * 32 + ((l >> 4) << 3) + j;
        int d  = n * 16 + (l & 15);
        wb[idx] = (unsigned short)f2bf(wts[(size_t)r * 64 + d]);
    }
}

// ---------------- kernel 1: fused KPConv (R9-exact, best measured) ------------
__global__ __launch_bounds__(256, 5) void k_conv(
    const unsigned short* __restrict__ fb, const float* __restrict__ qpts,
    const float* __restrict__ spts,  const int*   __restrict__ nidx,
    const float* __restrict__ kpts,  const unsigned short* __restrict__ wb,
    const float* __restrict__ bias,  const float* __restrict__ rowsum,
    float* __restrict__ conv_out, float* __restrict__ part_s, float* __restrict__ part_q)
{
    __shared__ __align__(16) short wl16[16 * 968];
    __shared__ __align__(16) float kp4[16][4];
    __shared__ float rcl[16];

    const int tid  = threadIdx.x;
    const int wv   = tid >> 6;
    const int lane = tid & 63;
    const int g    = lane >> 4;
    const int c16  = lane & 15;

    if (tid < 16) {
        if (tid < NK) {
            kp4[tid][0] = kpts[tid*3+0];
            kp4[tid][1] = kpts[tid*3+1];
            kp4[tid][2] = kpts[tid*3+2];
        } else {
            kp4[tid][0] = 1e8f; kp4[tid][1] = 1e8f; kp4[tid][2] = 1e8f;  // k=15 -> w=0
        }
        kp4[tid][3] = 0.f;
    }
    __syncthreads();

    const float kx = kp4[c16][0], ky = kp4[c16][1], kz = kp4[c16][2];

    const int qbase = blockIdx.x * QB;
    char*  WV  = (char*)wl16 + wv * 7424;
    float* XYP = (float*)WV;               // [(pp*64 + half*32 + h)*5 + comp]
    char*  FP  = WV + 2560;                // [32 h][144B], chunk XOR

    f32x4 pacc[4][4];
    #pragma unroll
    for (int a = 0; a < 4; a++)
        #pragma unroll
        for (int b = 0; b < 4; b++) pacc[a][b] = (f32x4){0.f,0.f,0.f,0.f};

    const int h    = lane & 31;
    const int half = lane >> 5;

    #pragma unroll
    for (int pp = 0; pp < 2; pp++) {
        const int qq = pp*2 + half;
        const int m  = qbase + wv*4 + qq;
        const float qx = qpts[m*3+0], qy = qpts[m*3+1], qz = qpts[m*3+2];
        const int  id  = nidx[(size_t)m * NH + h];
        const bool val = (id < NSUP);
        const int  ii  = val ? id : 0;
        const float dx = spts[ii*3+0]-qx, dy = spts[ii*3+1]-qy, dz = spts[ii*3+2]-qz;
        const float rs = rowsum[ii];
        unsigned long long bal = __ballot(val && rs > 0.f);
        int cA = __popcll(bal & 0xffffffffull); if (cA < 1) cA = 1;
        int cB = __popcll(bal >> 32);           if (cB < 1) cB = 1;
        if (lane == 0)  rcl[wv*4 + pp*2]     = 1.0f / (float)cA;
        if (lane == 32) rcl[wv*4 + pp*2 + 1] = 1.0f / (float)cB;
        const int si = (pp*64 + half*32 + h) * 5;
        XYP[si]     = val ? dx : 1e10f;
        XYP[si + 1] = dy;
        XYP[si + 2] = dz;
    }

    const int gr = lane >> 3;     // row slot 0..7
    const int gs = lane & 7;      // 16B chunk 0..7
    int   idA[4], idB[4];
    u32x4 vA[4], vB[4];
    {
        const int m0 = qbase + wv*4;
        #pragma unroll
        for (int i = 0; i < 4; i++) idA[i] = nidx[(size_t)m0*NH + i*8 + gr];
        #pragma unroll
        for (int i = 0; i < 4; i++) {
            const int id2 = (idA[i] < NSUP) ? idA[i] : 0;
            vA[i] = *(const u32x4*)((const char*)fb + (size_t)id2*128 + gs*16);
        }
        const int m1 = qbase + wv*4 + 1;
        #pragma unroll
        for (int i = 0; i < 4; i++) idB[i] = nidx[(size_t)m1*NH + i*8 + gr];
    }

    #pragma unroll
    for (int q = 0; q < 4; q++) {          // fully unrolled: all indices constant
        const int pp = q >> 1, e = q & 1;
        u32x4* vc  = (q & 1) ? vB  : vA;
        u32x4* vn  = (q & 1) ? vA  : vB;
        int*   idn = (q & 1) ? idA : idB;
        int*   idt = (q & 1) ? idB : idA;

        #pragma unroll
        for (int i = 0; i < 4; i++)
            *(u32x4*)(FP + (i*8 + gr)*144 + ((gs ^ i) << 4)) = vc[i];

        if (q < 3) {
            #pragma unroll
            for (int i = 0; i < 4; i++) {
                const int id2 = (idn[i] < NSUP) ? idn[i] : 0;
                vn[i] = *(const u32x4*)((const char*)fb + (size_t)id2*128 + gs*16);
            }
        }
        if (q < 2) {
            const int mn = qbase + wv*4 + q + 2;
            #pragma unroll
            for (int i = 0; i < 4; i++) idt[i] = nidx[(size_t)mn*NH + i*8 + gr];
        }

        union { unsigned short u[8]; bf16x8 v; } ua;
        #pragma unroll
        for (int j = 0; j < 8; j++) {
            const int xi = (pp*64 + e*32 + g*8 + j) * 5;
            const float px = XYP[xi], py = XYP[xi+1], pz = XYP[xi+2];
            const float ex = px - kx, ey = py - ky, ez = pz - kz;
            const float sq = fmaf(ex, ex, fmaf(ey, ey, ez * ez));
            const float w  = fmaxf(1.0f - sqrtf(sq) * INV_SIGMA, 0.f);
            ua.u[j] = (unsigned short)f2bf(w);
        }

        #pragma unroll
        for (int ct = 0; ct < 4; ct++) {
            const char* vb = FP + (g*8)*144
                           + (((((ct << 1) | (c16 >> 3)) ^ g) & 7) << 4)
                           + ((c16 & 7) << 1);
            union { unsigned short u[8]; bf16x8 v; } ub;
            #pragma unroll
            for (int j = 0; j < 8; j++)
                ub.u[j] = *(const unsigned short*)(vb + j*144);
            pacc[q][ct] = __builtin_amdgcn_mfma_f32_16x16x32_bf16(ua.v, ub.v, pacc[q][ct], 0, 0, 0);
        }
    }

    __syncthreads();     // phase-1 LDS dead; wl16 becomes the phase-2 A matrix

    #pragma unroll
    for (int qq = 0; qq < 4; qq++) {
        #pragma unroll
        for (int ct = 0; ct < 4; ct++) {
            #pragma unroll
            for (int i = 0; i < 4; i++) {
                const int kk = g*4 + i;
                if (kk < NK)
                    wl16[(wv*4 + qq)*968 + kk*64 + ct*16 + c16] = f2bf(pacc[qq][ct][i]);
            }
        }
    }
    __syncthreads();

    f32x4 facc = (f32x4){0.f,0.f,0.f,0.f};
    const int z = lane >> 4;
    const short* ap = wl16 + c16*968 + z*8;
    const unsigned short* bp = wb + ((size_t)(wv * 64 + lane)) * 8;
    #pragma unroll 6
    for (int ks = 0; ks < 30; ks++) {
        bf16x8 a = *(const bf16x8*)(ap + ks*32);
        bf16x8 b = *(const bf16x8*)(bp + (size_t)ks*2048);
        facc = __builtin_amdgcn_mfma_f32_16x16x32_bf16(a, b, facc, 0, 0, 0);
    }

    const int   d  = wv*16 + c16;
    const float bs = bias[d];
    float gl = 0.f, gq = 0.f;
    #pragma unroll
    for (int i = 0; i < 4; i++) {
        const int row = z*4 + i;
        const float y = facc[i] * rcl[row] + bs;
        conv_out[(size_t)(qbase + row)*64 + d] = y;
        gl += y;
        gq = fmaf(y, y, gq);
    }
    #pragma unroll
    for (int msk = 1; msk <= 4; msk <<= 1) { gl += __shfl_xor(gl, msk); gq += __shfl_xor(gq, msk); }
    gl += __shfl_xor(gl, 16); gq += __shfl_xor(gq, 16);
    gl += __shfl_xor(gl, 32); gq += __shfl_xor(gq, 32);
    if ((lane & 55) == 0) {
        const int grp = wv*2 + (lane >> 3);
        part_s[(size_t)blockIdx.x * 8 + grp] = gl;
        part_q[(size_t)blockIdx.x * 8 + grp] = gq;
    }
}

// ---------------- kernel 2: fused deterministic stats + GN + LeakyReLU --------
__global__ __launch_bounds__(256) void k_apply(float* __restrict__ out,
                                               const float* __restrict__ part_s,
                                               const float* __restrict__ part_q,
                                               const float* __restrict__ gamma,
                                               const float* __restrict__ beta) {
    __shared__ double ds[32][8], dq[32][8];
    __shared__ float st[16];
    const int t = threadIdx.x;

    // every block computes the SAME reduction in the SAME order -> identical stats
    {
        const int gg = t & 7, chunk = t >> 3;
        const int per = (NBLK + 31) / 32;          // 98
        int lo = chunk * per, hi = lo + per; if (hi > NBLK) hi = NBLK;
        double s0 = 0.0, s1 = 0.0, s2 = 0.0, s3 = 0.0;
        double q0 = 0.0, q1 = 0.0, q2 = 0.0, q3 = 0.0;
        int i = lo;
        for (; i + 3 < hi; i += 4) {
            s0 += (double)part_s[(size_t)(i+0) * 8 + gg];
            s1 += (double)part_s[(size_t)(i+1) * 8 + gg];
            s2 += (double)part_s[(size_t)(i+2) * 8 + gg];
            s3 += (double)part_s[(size_t)(i+3) * 8 + gg];
            q0 += (double)part_q[(size_t)(i+0) * 8 + gg];
            q1 += (double)part_q[(size_t)(i+1) * 8 + gg];
            q2 += (double)part_q[(size_t)(i+2) * 8 + gg];
            q3 += (double)part_q[(size_t)(i+3) * 8 + gg];
        }
        for (; i < hi; i++) {
            s0 += (double)part_s[(size_t)i * 8 + gg];
            q0 += (double)part_q[(size_t)i * 8 + gg];
        }
        ds[chunk][gg] = (s0 + s1) + (s2 + s3);
        dq[chunk][gg] = (q0 + q1) + (q2 + q3);
        __syncthreads();
        if (t < 8) {
            double S = 0.0, Q = 0.0;
            for (int cix = 0; cix < 32; cix++) { S += ds[cix][t]; Q += dq[cix][t]; }
            const double cnt = (double)(64 / NG) * (double)NQ;   // 400000
            double mean = S / cnt;
            double var  = Q / cnt - mean * mean;
            st[t]     = (float)mean;
            st[8 + t] = (float)(1.0 / sqrt(var + (double)GN_EPS));
        }
        __syncthreads();
    }

    // normalize + affine + LeakyReLU, in place on d_out (same thread R+W)
    const int n4 = NQ * 64 / 4;
    for (int idx = blockIdx.x * 256 + t; idx < n4; idx += gridDim.x * 256) {
        float4 v = ((const float4*)out)[idx];
        const int c4 = idx & 15;
        const int g  = c4 >> 1;
        const float mean = st[g], istd = st[8 + g];
        const float4 ga = ((const float4*)gamma)[c4];
        const float4 be = ((const float4*)beta)[c4];
        float4 r;
        r.x = (v.x - mean) * istd * ga.x + be.x; r.x = r.x >= 0.f ? r.x : NEG * r.x;
        r.y = (v.y - mean) * istd * ga.y + be.y; r.y = r.y >= 0.f ? r.y : NEG * r.y;
        r.z = (v.z - mean) * istd * ga.z + be.z; r.z = r.z >= 0.f ? r.z : NEG * r.z;
        r.w = (v.w - mean) * istd * ga.w + be.w; r.w = r.w >= 0.f ? r.w : NEG * r.w;
        ((float4*)out)[idx] = r;
    }
}

extern "C" void kernel_launch(void* const* d_in, const int* in_sizes, int n_in,
                              void* d_out, int out_size, void* d_ws, size_t ws_size,
                              hipStream_t stream) {
    const float* sfeats = (const float*)d_in[0];
    const float* qpts   = (const float*)d_in[1];
    const float* spts   = (const float*)d_in[2];
    const int*   nidx   = (const int*)  d_in[3];
    const float* kpts   = (const float*)d_in[4];
    const float* wts    = (const float*)d_in[5];
    const float* bias   = (const float*)d_in[6];
    const float* gamma  = (const float*)d_in[7];
    const float* beta   = (const float*)d_in[8];

    float* ws = (float*)d_ws;
    float*          rowsum = ws + OFF_ROWSUM;
    unsigned short* fb     = (unsigned short*)(ws + OFF_FB);
    unsigned short* wb     = (unsigned short*)(ws + OFF_WB);
    float*          ps     = ws + OFF_PS;
    float*          pq     = ws + OFF_PQ;
    float*          out    = (float*)d_out;

    k_prep <<<dim3(3365), dim3(256), 0, stream>>>(sfeats, rowsum, fb, wts, wb);
    k_conv <<<dim3(NBLK), dim3(256), 0, stream>>>(fb, qpts, spts, nidx, kpts,
                                                  wb, bias, rowsum, out, ps, pq);
    k_apply<<<dim3(512),  dim3(256), 0, stream>>>(out, ps, pq, gamma, beta);
}